// Round 1
// 938.457 us; speedup vs baseline: 1.0082x; 1.0082x over previous
//
#include <hip/hip_runtime.h>
#include <hip/hip_bf16.h>
#include <stdint.h>

// x:(4,4096,4096) f32, weight:(4096,4096) f32, bias:(4096,) f32,
// fixed_base:(32,) f32, fixed_sign_flag:(32,) f32 -> out:(4,4096,4096) f32.
// M=16384, N=4096, K=4096. Group size 128.
#define H_DIM   4096
#define OUT_DIM 4096
#define M_TOTAL 16384
#define NGROUP  32
#define GSZ     128

// 256x256 tile, BK=64, 8 waves (2M x 4N), 512 threads — 8-phase schedule.
#define BM 256
#define BN 256
#define BK 64
#define NT (H_DIM / BK)   // 64 K-tiles

typedef float  f32x4  __attribute__((ext_vector_type(4)));
typedef __bf16 bf16x8 __attribute__((ext_vector_type(8)));

// async global->LDS, 16B/lane. LDS dest = wave-uniform base + lane*16 (fixed);
// the global source address is per-lane (that's where the swizzle goes).
__device__ __forceinline__ void ld_g2l_16(const void* gptr, void* ldsptr) {
  __builtin_amdgcn_global_load_lds(
      (const __attribute__((address_space(1))) uint32_t*)gptr,
      (__attribute__((address_space(3))) uint32_t*)ldsptr,
      16, 0, 0);
}

// ---------------------------------------------------------------------------
// Pre-pass 1: quotient/remainder fake-quant of x -> bf16 x'.
// Grid-stride, 2048 blocks. 16 lanes per 128-elem group, 8 floats/lane,
// bf16x8 (16B) stores. (Old version: 65536 tiny blocks — dispatch-bound.)
__global__ void quant_x_kernel(const float* __restrict__ x,
                               const float* __restrict__ fixed_base,
                               const float* __restrict__ fixed_sign,
                               __hip_bfloat16* __restrict__ xq) {
  const int  tid = threadIdx.x;
  const int  lg  = tid & 15;                        // lane within 16-lane group
  const long NG  = (long)M_TOTAL * NGROUP;          // 524288 group instances
  for (long gi = (long)blockIdx.x * 16 + (tid >> 4); gi < NG;
       gi += (long)gridDim.x * 16) {
    const int  g   = (int)(gi & (NGROUP - 1));
    const long off = (gi >> 5) * H_DIM + (long)g * GSZ + lg * 8;

    const float4 v0 = *(const float4*)(x + off);
    const float4 v1 = *(const float4*)(x + off + 4);
    const float s  = fixed_sign[g];
    const float b  = fixed_base[g];
    const float hb = b * 0.5f;
    const float sb = s * b;

    float q[8], r[8];
    const float xin[8] = {v0.x, v0.y, v0.z, v0.w, v1.x, v1.y, v1.z, v1.w};
#pragma unroll
    for (int k = 0; k < 8; ++k) {
      q[k] = (xin[k] * s >= hb) ? 1.0f : 0.0f;
      r[k] = xin[k] - sb * q[k];
    }
    float m = 0.0f;
#pragma unroll
    for (int k = 0; k < 8; ++k) m = fmaxf(m, fabsf(r[k]));
#pragma unroll
    for (int d = 8; d > 0; d >>= 1) m = fmaxf(m, __shfl_xor(m, d, 64));  // 16-lane reduce
    m = fmaxf(m, 1e-8f);

    const float scale = m / 7.0f;
    const float inv_s = 7.0f / m;
    bf16x8 o;
#pragma unroll
    for (int k = 0; k < 8; ++k) {
      float t = fminf(fmaxf(rintf(r[k] * inv_s), -8.0f), 7.0f);  // rintf = half-even = jnp.round
      o[k] = (__bf16)(q[k] * sb + t * scale);
    }
    *(bf16x8*)(xq + off) = o;
  }
}

// ---------------------------------------------------------------------------
// Pre-pass 2: weight f32 -> bf16, grid-stride, 8 floats/thread.
__global__ void wconv_kernel(const float* __restrict__ w,
                             __hip_bfloat16* __restrict__ wq) {
  const size_t total = (size_t)OUT_DIM * H_DIM / 8;
  for (size_t i = (size_t)blockIdx.x * blockDim.x + threadIdx.x; i < total;
       i += (size_t)gridDim.x * blockDim.x) {
    const size_t e  = i * 8;
    const float4 v0 = *(const float4*)(w + e);
    const float4 v1 = *(const float4*)(w + e + 4);
    bf16x8 o;
    o[0] = (__bf16)v0.x; o[1] = (__bf16)v0.y; o[2] = (__bf16)v0.z; o[3] = (__bf16)v0.w;
    o[4] = (__bf16)v1.x; o[5] = (__bf16)v1.y; o[6] = (__bf16)v1.z; o[7] = (__bf16)v1.w;
    *(bf16x8*)(wq + e) = o;
  }
}

// ---------------------------------------------------------------------------
// GEMM: C[M,N] = A[M,K] * W[N,K]^T + bias, bf16 in / f32 out.
// 256^2 8-phase schedule (T1+T2+T3+T4+T5):
//  - LDS [mat][dbuf][ksub][256 rows][32 bf16], 128 KiB, K-split half-tiles.
//  - Half-tile h = (mat, ksub) of a K-tile: 256x32 bf16 = 16 KB = 2 gloads/thread.
//  - Steady state, during tile t (4 phases):
//      P0: read A(s0,m0..3)+B(s0) | stage A-K1(t+1)->buf^1 | bar,lgkm0,prio,16 MFMA,bar
//      P1: read A(s0,m4..7)       | stage B-K1(t+1)->buf^1 | ... vmcnt(8), bar
//      P2: read A(s1,m0..3)+B(s1) | stage A-K0(t+2)->buf   | ... (safe: s0 reads done @P1)
//      P3: read A(s1,m4..7)       | stage B-K0(t+2)->buf   | ... vmcnt(8), bar
//    4 half-tiles (8 loads) always in flight; vmcnt never drained in main loop.
//  - Bank swizzle: global chunk c of row r stored at LDS chunk c^( (r>>1)&3 )
//    (involution; applied on the pre-swizzled GLOBAL source + on the read).
//    16 lanes/quad -> 8 distinct 16B slots x 2 lanes = 2-way = free.
#define VM8 0x0f78  /* vmcnt(8)  */
#define VM4 0x0f74  /* vmcnt(4)  */
#define VM0 0x0f70  /* vmcnt(0)  */
#define LGK 0xc07f  /* lgkmcnt(0) only */

#define BAR()   do { asm volatile("" ::: "memory"); __builtin_amdgcn_s_barrier(); \
                     asm volatile("" ::: "memory"); } while (0)
#define LGKM0() __builtin_amdgcn_s_waitcnt(LGK)
#define PRIO1() __builtin_amdgcn_s_setprio(1)
#define PRIO0() __builtin_amdgcn_s_setprio(0)

// stage one K-half: matrix X (0=A,1=B), dest buffer D, ksub S, k offset KT
#define STAGE(X, D, S, KT) do {                                                \
    const __hip_bfloat16* _gp = ((X) == 0 ? pA : pB) + (KT) + (S) * 32;        \
    __bf16* _lp = &lds[(X)][(D)][(S)][sR][sLC8];                               \
    ld_g2l_16(_gp, _lp);                                                       \
    ld_g2l_16(_gp + (size_t)128 * H_DIM, _lp + 128 * 32);                      \
  } while (0)

#define LDA4(DD, S, MH) do {                                                   \
    _Pragma("unroll")                                                          \
    for (int _m = 0; _m < 4; ++_m)                                             \
      af[_m] = *(const bf16x8*)&lds[0][DD][S][rdA + ((MH) * 4 + _m) * 16][sw8];\
  } while (0)

#define LDB4(DD, S) do {                                                       \
    _Pragma("unroll")                                                          \
    for (int _n = 0; _n < 4; ++_n)                                             \
      bf[_n] = *(const bf16x8*)&lds[1][DD][S][rdB + _n * 16][sw8];             \
  } while (0)

#define MFMA16(MH) do {                                                        \
    _Pragma("unroll")                                                          \
    for (int _m = 0; _m < 4; ++_m)                                             \
      _Pragma("unroll")                                                        \
      for (int _n = 0; _n < 4; ++_n)                                           \
        acc[(MH) * 4 + _m][_n] = __builtin_amdgcn_mfma_f32_16x16x32_bf16(      \
            af[_m], bf[_n], acc[(MH) * 4 + _m][_n], 0, 0, 0);                  \
  } while (0)

#define TILE_STEP(DD, SK1, SK0, KT1, KT0, VM1, VM2) do {                       \
    /* P0: s=0, m-half 0 */                                                    \
    LDA4(DD, 0, 0); LDB4(DD, 0);                                               \
    if (SK1) { STAGE(0, (DD) ^ 1, 1, KT1); }                                   \
    BAR(); LGKM0(); PRIO1(); MFMA16(0); PRIO0(); BAR();                        \
    /* P1: s=0, m-half 1 */                                                    \
    LDA4(DD, 0, 1);                                                            \
    if (SK1) { STAGE(1, (DD) ^ 1, 1, KT1); }                                   \
    BAR(); LGKM0(); PRIO1(); MFMA16(1); PRIO0();                               \
    __builtin_amdgcn_s_waitcnt(VM1); BAR();                                    \
    /* P2: s=1, m-half 0 (stage overwrites own-buf s0: reads done at P1) */    \
    LDA4(DD, 1, 0); LDB4(DD, 1);                                               \
    if (SK0) { STAGE(0, DD, 0, KT0); }                                         \
    BAR(); LGKM0(); PRIO1(); MFMA16(0); PRIO0(); BAR();                        \
    /* P3: s=1, m-half 1 */                                                    \
    LDA4(DD, 1, 1);                                                            \
    if (SK0) { STAGE(1, DD, 0, KT0); }                                         \
    BAR(); LGKM0(); PRIO1(); MFMA16(1); PRIO0();                               \
    __builtin_amdgcn_s_waitcnt(VM2); BAR();                                    \
  } while (0)

__global__ __launch_bounds__(512, 2)
void gemm_bt_kernel(const __hip_bfloat16* __restrict__ A,
                    const __hip_bfloat16* __restrict__ W,
                    const float* __restrict__ bias,
                    float* __restrict__ C) {
  __shared__ __bf16 lds[2][2][2][256][32];   // [mat][dbuf][ksub][row][k] = 128 KiB

  const int tid  = threadIdx.x;
  const int wave = tid >> 6;
  const int lane = tid & 63;
  const int quad = lane >> 4;
  const int l15  = lane & 15;
  const int wm   = wave >> 2;                // 0..1 (M)
  const int wn   = wave & 3;                 // 0..3 (N)

  // XCD-aware bijective swizzle: 1024 blocks, 128 contiguous per XCD,
  // within a slab nt cycles fastest (A-panel L2-resident, W from LLC).
  const int bid = blockIdx.x;
  const int vid = (bid & 7) * 128 + (bid >> 3);
  const long rowBase = (long)(vid >> 4) * BM;
  const long colBase = (long)(vid & 15) * BN;

  // staging geometry: thread covers rows sR and sR+128, LDS chunk tid&3,
  // global chunk (tid&3)^((sR>>1)&3)  [inverse of the read swizzle]
  const int sR   = tid >> 2;
  const int sLC8 = (tid & 3) * 8;
  const int sCg  = (tid & 3) ^ ((sR >> 1) & 3);
  const __hip_bfloat16* pA = A + (rowBase + sR) * H_DIM + sCg * 8;
  const __hip_bfloat16* pB = W + (colBase + sR) * H_DIM + sCg * 8;

  // read geometry: row r, k-chunk quad -> LDS chunk quad^((r>>1)&3).
  // (r>>1)&3 is invariant under +16*m and wave offsets (all mult. of 4 rows x2).
  const int rdA = wm * 128 + l15;
  const int rdB = wn * 64 + l15;
  const int sw8 = (quad ^ ((l15 >> 1) & 3)) * 8;

  f32x4 acc[8][4] = {};
  bf16x8 af[4], bf[4];

  // prologue: K0(0),K1(0),K0(1) staged; vmcnt(8) -> K0(0) complete.
  STAGE(0, 0, 0, 0);  STAGE(1, 0, 0, 0);
  STAGE(0, 0, 1, 0);  STAGE(1, 0, 1, 0);
  STAGE(0, 1, 0, BK); STAGE(1, 1, 0, BK);
  __builtin_amdgcn_s_waitcnt(VM8);
  BAR();

  // main loop: tiles 0..61 (2 per iteration, compile-time dbuf parity)
  for (int t = 0; t < NT - 2; t += 2) {
    TILE_STEP(0, true, true, (t + 1) * BK, (t + 2) * BK, VM8, VM8);
    TILE_STEP(1, true, true, (t + 2) * BK, (t + 3) * BK, VM8, VM8);
  }
  // tile 62: no K0 prefetch; drain to 4 (K1(63) stays in flight)
  TILE_STEP(0, true, false, (NT - 1) * BK, 0, VM8, VM4);
  // tile 63: no stages; wait K1(63) before its s1 phases
  TILE_STEP(1, false, false, 0, 0, VM0, VM0);

  // epilogue: C/D layout col = lane&15, row = quad*4 + reg (m89-verified)
  float bv[4];
#pragma unroll
  for (int n = 0; n < 4; ++n)
    bv[n] = bias[colBase + wn * 64 + n * 16 + l15];
#pragma unroll
  for (int m = 0; m < 8; ++m) {
#pragma unroll
    for (int n = 0; n < 4; ++n) {
      const long r0 = rowBase + wm * 128 + m * 16 + quad * 4;
      const long c  = colBase + wn * 64 + n * 16 + l15;
#pragma unroll
      for (int rg = 0; rg < 4; ++rg)
        C[(r0 + rg) * OUT_DIM + c] = acc[m][n][rg] + bv[n];
    }
  }
}

// ---------------------------------------------------------------------------
extern "C" void kernel_launch(void* const* d_in, const int* in_sizes, int n_in,
                              void* d_out, int out_size, void* d_ws, size_t ws_size,
                              hipStream_t stream) {
  const float* x          = (const float*)d_in[0];
  const float* weight     = (const float*)d_in[1];
  const float* bias       = (const float*)d_in[2];
  const float* fixed_base = (const float*)d_in[3];
  const float* fixed_sign = (const float*)d_in[4];
  float* out = (float*)d_out;

  __hip_bfloat16* xq = (__hip_bfloat16*)d_ws;                  // 128 MiB
  __hip_bfloat16* wq = xq + (size_t)M_TOTAL * H_DIM;           // +32 MiB

  quant_x_kernel<<<2048, 256, 0, stream>>>(x, fixed_base, fixed_sign, xq);
  wconv_kernel<<<2048, 256, 0, stream>>>(weight, wq);

  gemm_bt_kernel<<<dim3((M_TOTAL / BM) * (OUT_DIM / BN)), 512, 0, stream>>>(xq, wq, bias, out);
}

// Round 2
// 921.738 us; speedup vs baseline: 1.0265x; 1.0181x over previous
//
#include <hip/hip_runtime.h>
#include <hip/hip_bf16.h>
#include <stdint.h>

// x:(4,4096,4096) f32, weight:(4096,4096) f32, bias:(4096,) f32,
// fixed_base:(32,) f32, fixed_sign_flag:(32,) f32 -> out:(4,4096,4096) f32.
// M=16384, N=4096, K=4096. Group size 128.
#define H_DIM   4096
#define OUT_DIM 4096
#define M_TOTAL 16384
#define NGROUP  32
#define GSZ     128

// 256x256 tile, BK=64, 8 waves (2M x 4N), 512 threads — 8-phase pipelined.
#define BM 256
#define BN 256
#define BK 64
#define NT (H_DIM / BK)   // 64 K-tiles

typedef float  f32x4  __attribute__((ext_vector_type(4)));
typedef __bf16 bf16x8 __attribute__((ext_vector_type(8)));

__device__ __forceinline__ void ld_g2l_16(const void* gptr, void* ldsptr) {
  __builtin_amdgcn_global_load_lds(
      (const __attribute__((address_space(1))) uint32_t*)gptr,
      (__attribute__((address_space(3))) uint32_t*)ldsptr,
      16, 0, 0);
}

// ---------------------------------------------------------------------------
// Fused pre-pass: quant(x)->bf16 xq  AND  weight f32->bf16 wq, one dispatch.
// Virtual blocks 0..65535: quant (8 groups/block, 32 lanes/group, float4).
// Virtual blocks 65536..73727: wconv (2048 floats/block).
__global__ void prep_kernel(const float* __restrict__ x,
                            const float* __restrict__ fixed_base,
                            const float* __restrict__ fixed_sign,
                            __hip_bfloat16* __restrict__ xq,
                            const float* __restrict__ w,
                            __hip_bfloat16* __restrict__ wq) {
  const int tid = threadIdx.x;
  const int NVB_Q = (M_TOTAL * NGROUP) / 8;          // 65536
  const int NVB   = NVB_Q + (OUT_DIM * H_DIM) / 2048; // +8192
  for (int vb = blockIdx.x; vb < NVB; vb += gridDim.x) {
    if (vb < NVB_Q) {
      const long gi  = (long)vb * 8 + (tid >> 5);
      const int  lg  = tid & 31;
      const int  g   = (int)(gi & (NGROUP - 1));
      const long off = (gi >> 5) * H_DIM + (long)g * GSZ + lg * 4;

      const float4 xv = *(const float4*)(x + off);
      const float  s  = fixed_sign[g];
      const float  b  = fixed_base[g];
      const float  hb = b * 0.5f;
      const float  sb = s * b;

      float q[4], r[4];
      const float xin[4] = {xv.x, xv.y, xv.z, xv.w};
#pragma unroll
      for (int k = 0; k < 4; ++k) {
        q[k] = (xin[k] * s >= hb) ? 1.0f : 0.0f;
        r[k] = xin[k] - sb * q[k];
      }
      float m = fmaxf(fmaxf(fabsf(r[0]), fabsf(r[1])), fmaxf(fabsf(r[2]), fabsf(r[3])));
#pragma unroll
      for (int d = 16; d > 0; d >>= 1) m = fmaxf(m, __shfl_xor(m, d, 64));  // stays in 32-lane group
      m = fmaxf(m, 1e-8f);

      const float scale = m / 7.0f;
      const float inv_s = 7.0f / m;
      typedef __bf16 bf16x4 __attribute__((ext_vector_type(4)));
      bf16x4 o;
#pragma unroll
      for (int k = 0; k < 4; ++k) {
        float t = fminf(fmaxf(rintf(r[k] * inv_s), -8.0f), 7.0f);  // rintf = half-even = jnp.round
        o[k] = (__bf16)(q[k] * sb + t * scale);
      }
      *(bf16x4*)(xq + off) = o;
    } else {
      const size_t e  = ((size_t)(vb - NVB_Q) * 256 + tid) * 8;
      const float4 v0 = *(const float4*)(w + e);
      const float4 v1 = *(const float4*)(w + e + 4);
      bf16x8 o;
      o[0] = (__bf16)v0.x; o[1] = (__bf16)v0.y; o[2] = (__bf16)v0.z; o[3] = (__bf16)v0.w;
      o[4] = (__bf16)v1.x; o[5] = (__bf16)v1.y; o[6] = (__bf16)v1.z; o[7] = (__bf16)v1.w;
      *(bf16x8*)(wq + e) = o;
    }
  }
}

// ---------------------------------------------------------------------------
// GEMM: C[M,N] = A[M,K] * W[N,K]^T + bias, bf16 in / f32 out.
// 256^2 8-phase schedule WITH pipelined register loads (ping-pong frag sets):
//   phase φ: [STAGE per schedule][vmcnt if scheduled][BAR_a]
//            [issue ds_reads(φ+1) into other set][MFMA(φ) on current set][BAR_b]
// ds_read latency of φ+1 hides under MFMA(φ); compiler emits counted lgkmcnt.
// Hazard ledger (verified):
//  - reads(φ+1) issued after BAR_a(φ), which follows the vmcnt guaranteeing
//    their staged data: s1 reads after vmcnt(8)@P1, next-tile s0 reads after
//    vmcnt(8)@P3 (tail: VM4/VM0).
//  - STAGE at φ start overwrites a region whose reads drained before
//    MFMA(φ-1) < BAR_b(φ-1), which precedes the STAGE. Safe.
//  - vmcnt never drains to 0 in the main loop (8 loads / 4 half-tiles in flight).
#define VM8 0x0f78  /* vmcnt(8)  */
#define VM4 0x0f74  /* vmcnt(4)  */
#define VM0 0x0f70  /* vmcnt(0)  */

#define BAR()   do { asm volatile("" ::: "memory"); __builtin_amdgcn_s_barrier(); \
                     asm volatile("" ::: "memory"); } while (0)
#define PRIO1() __builtin_amdgcn_s_setprio(1)
#define PRIO0() __builtin_amdgcn_s_setprio(0)

// stage one K-half: matrix X (0=A,1=B), dest buffer D, ksub S, k offset KT
#define STAGE(X, D, S, KT) do {                                                \
    const __hip_bfloat16* _gp = ((X) == 0 ? pA : pB) + (KT) + (S) * 32;        \
    __bf16* _lp = &lds[(X)][(D)][(S)][sR][sLC8];                               \
    ld_g2l_16(_gp, _lp);                                                       \
    ld_g2l_16(_gp + (size_t)128 * H_DIM, _lp + 128 * 32);                      \
  } while (0)

#define RD_A(SET, DD, S, MH) do {                                              \
    _Pragma("unroll")                                                          \
    for (int _m = 0; _m < 4; ++_m)                                             \
      SET[_m] = *(const bf16x8*)&lds[0][DD][S][rdA + ((MH) * 4 + _m) * 16][sw8];\
  } while (0)

#define RD_B(SET, DD, S) do {                                                  \
    _Pragma("unroll")                                                          \
    for (int _n = 0; _n < 4; ++_n)                                             \
      SET[_n] = *(const bf16x8*)&lds[1][DD][S][rdB + _n * 16][sw8];            \
  } while (0)

#define MM(AF, BF, MH) do {                                                    \
    _Pragma("unroll")                                                          \
    for (int _m = 0; _m < 4; ++_m)                                             \
      _Pragma("unroll")                                                        \
      for (int _n = 0; _n < 4; ++_n)                                           \
        acc[(MH) * 4 + _m][_n] = __builtin_amdgcn_mfma_f32_16x16x32_bf16(      \
            AF[_m], BF[_n], acc[(MH) * 4 + _m][_n], 0, 0, 0);                  \
  } while (0)

// One K-tile = 4 phases. Entering: af0 = A(D,s0,mh0), bf0 = B(D,s0) loaded.
// Exiting (if DORD3): af0/bf0 = next tile's (D^1, s0) frags.
#define TILE(D, SK1, KT1, SK0, KT0, VMA, VMB, DORD3) do {                      \
    /* P0 */                                                                   \
    if (SK1) { STAGE(0, (D) ^ 1, 1, KT1); }                                    \
    BAR();                                                                     \
    RD_A(af1, D, 0, 1);                                                        \
    PRIO1(); MM(af0, bf0, 0); PRIO0();                                         \
    BAR();                                                                     \
    /* P1 */                                                                   \
    if (SK1) { STAGE(1, (D) ^ 1, 1, KT1); }                                    \
    __builtin_amdgcn_s_waitcnt(VMA);                                           \
    BAR();                                                                     \
    RD_A(af0, D, 1, 0); RD_B(bf1, D, 1);                                       \
    PRIO1(); MM(af1, bf0, 1); PRIO0();                                         \
    BAR();                                                                     \
    /* P2 */                                                                   \
    if (SK0) { STAGE(0, D, 0, KT0); }                                          \
    BAR();                                                                     \
    RD_A(af1, D, 1, 1);                                                        \
    PRIO1(); MM(af0, bf1, 0); PRIO0();                                         \
    BAR();                                                                     \
    /* P3 */                                                                   \
    if (SK0) { STAGE(1, D, 0, KT0); }                                          \
    __builtin_amdgcn_s_waitcnt(VMB);                                           \
    BAR();                                                                     \
    if (DORD3) { RD_A(af0, (D) ^ 1, 0, 0); RD_B(bf0, (D) ^ 1, 0); }            \
    PRIO1(); MM(af1, bf1, 1); PRIO0();                                         \
    BAR();                                                                     \
  } while (0)

__global__ __launch_bounds__(512, 2)
void gemm_bt_kernel(const __hip_bfloat16* __restrict__ A,
                    const __hip_bfloat16* __restrict__ W,
                    const float* __restrict__ bias,
                    float* __restrict__ C) {
  __shared__ __bf16 lds[2][2][2][256][32];   // [mat][dbuf][ksub][row][k] = 128 KiB

  const int tid  = threadIdx.x;
  const int lane = tid & 63;
  const int wave = tid >> 6;
  const int quad = lane >> 4;
  const int l15  = lane & 15;
  const int wm   = wave >> 2;                // 0..1 (M)
  const int wn   = wave & 3;                 // 0..3 (N)

  // XCD-aware bijective swizzle: 1024 blocks, 128 contiguous per XCD.
  const int bid = blockIdx.x;
  const int vid = (bid & 7) * 128 + (bid >> 3);
  const long rowBase = (long)(vid >> 4) * BM;
  const long colBase = (long)(vid & 15) * BN;

  // staging: thread covers rows sR,sR+128; LDS chunk tid&3 carries global
  // chunk (tid&3)^((sR>>1)&3)  [inverse of the read swizzle]
  const int sR   = tid >> 2;
  const int sLC8 = (tid & 3) * 8;
  const int sCg  = (tid & 3) ^ ((sR >> 1) & 3);
  const __hip_bfloat16* pA = A + (rowBase + sR) * H_DIM + sCg * 8;
  const __hip_bfloat16* pB = W + (colBase + sR) * H_DIM + sCg * 8;

  // reads: row r, k-chunk quad -> LDS chunk quad^((r>>1)&3); (r>>1)&3==(l15>>1)&3
  const int rdA = wm * 128 + l15;
  const int rdB = wn * 64 + l15;
  const int sw8 = (quad ^ ((l15 >> 1) & 3)) * 8;

  f32x4  acc[8][4] = {};
  bf16x8 af0[4], af1[4], bf0[4], bf1[4];

  // prologue: K0(0),K1(0),K0(1) staged (12 loads); vmcnt(8) -> K0(0) arrived.
  STAGE(0, 0, 0, 0);  STAGE(1, 0, 0, 0);
  STAGE(0, 0, 1, 0);  STAGE(1, 0, 1, 0);
  STAGE(0, 1, 0, BK); STAGE(1, 1, 0, BK);
  __builtin_amdgcn_s_waitcnt(VM8);
  BAR();
  RD_A(af0, 0, 0, 0); RD_B(bf0, 0, 0);

  // main loop: tiles 0..61; in-flight at each tile entry: {K1(t):4, K0(t+1):4}
  for (int t = 0; t < NT - 2; t += 2) {
    TILE(0, true, (t + 1) * BK, true, (t + 2) * BK, VM8, VM8, true);
    TILE(1, true, (t + 2) * BK, true, (t + 3) * BK, VM8, VM8, true);
  }
  // tile 62: stage K1(63) only; VM4 drains K0(63) for the last tile's s0 reads
  TILE(0, true, (NT - 1) * BK, false, 0, VM8, VM4, true);
  // tile 63: no stages; VM0 drains K1(63); no next-tile reads
  TILE(1, false, 0, false, 0, VM0, VM0, false);

  // epilogue: C/D layout col = lane&15, row = quad*4 + reg (m89-verified)
#pragma unroll
  for (int m = 0; m < 8; ++m) {
#pragma unroll
    for (int n = 0; n < 4; ++n) {
      const long r0 = rowBase + wm * 128 + m * 16 + quad * 4;
      const long c  = colBase + wn * 64 + n * 16 + l15;
      const float bv = bias[c];
#pragma unroll
      for (int rg = 0; rg < 4; ++rg)
        C[(r0 + rg) * OUT_DIM + c] = acc[m][n][rg] + bv;
    }
  }
}

// ---------------------------------------------------------------------------
extern "C" void kernel_launch(void* const* d_in, const int* in_sizes, int n_in,
                              void* d_out, int out_size, void* d_ws, size_t ws_size,
                              hipStream_t stream) {
  const float* x          = (const float*)d_in[0];
  const float* weight     = (const float*)d_in[1];
  const float* bias       = (const float*)d_in[2];
  const float* fixed_base = (const float*)d_in[3];
  const float* fixed_sign = (const float*)d_in[4];
  float* out = (float*)d_out;

  __hip_bfloat16* xq = (__hip_bfloat16*)d_ws;                  // 128 MiB
  __hip_bfloat16* wq = xq + (size_t)M_TOTAL * H_DIM;           // +32 MiB

  prep_kernel<<<2048, 256, 0, stream>>>(x, fixed_base, fixed_sign, xq, weight, wq);

  gemm_bt_kernel<<<dim3((M_TOTAL / BM) * (OUT_DIM / BN)), 512, 0, stream>>>(xq, wq, bias, out);
}